// Round 6
// baseline (420.610 us; speedup 1.0000x reference)
//
#include <hip/hip_runtime.h>
#include <hip/hip_bf16.h>

#define BB 8
#define CC 512
#define HO 64
#define HP 66
#define NPIX (BB*HO*HO)   // 32768

typedef float f32x4 __attribute__((ext_vector_type(4)));
typedef float f32x16 __attribute__((ext_vector_type(16)));
typedef __bf16 bf16x8 __attribute__((ext_vector_type(8)));
using bf16 = __hip_bfloat16;

__device__ __forceinline__ void gload16(const void* g, void* l) {
    __builtin_amdgcn_global_load_lds((const __attribute__((address_space(1))) void*)g,
                                     (__attribute__((address_space(3))) void*)l, 16, 0, 0);
}

__device__ __forceinline__ float waveRedSum(float v) {
    #pragma unroll
    for (int off = 32; off; off >>= 1) v += __shfl_down(v, off);
    return v;
}

// thread t -> (i = t&511, o = t>>9). Reads W[i][o][0..8] (contiguous 36B),
// writes S2ho[o][i] = he^2 * sum W^2, and keffT[tap][o][i] = he*W[i][o][8-tap].
__global__ void prep_weights(const float* __restrict__ Wsrc, float* __restrict__ S2ho,
                             bf16* __restrict__ keffT, float he) {
    int t = blockIdx.x * blockDim.x + threadIdx.x;
    int i = t & (CC-1), o = t >> 9;
    const float* wp = Wsrc + (i*CC + o)*9;
    float v[9]; float s2 = 0.f;
    #pragma unroll
    for (int k = 0; k < 9; ++k) { v[k] = wp[k] * he; s2 += v[k]*v[k]; }
    S2ho[o*CC + i] = s2;
    #pragma unroll
    for (int tp = 0; tp < 9; ++tp) keffT[(tp*CC + o)*CC + i] = (bf16)v[8 - tp];
}

// one wave per (set, b, i): style[b,i] = sum_d w[b,d]*A[i,d]/sqrt(512) + Ab[i]
__global__ void style_kernel(const float* __restrict__ w,
                             const float* __restrict__ A1, const float* __restrict__ A1b,
                             const float* __restrict__ A2, const float* __restrict__ A2b,
                             float* __restrict__ s1, float* __restrict__ s2) {
    int wid = (blockIdx.x * blockDim.x + threadIdx.x) >> 6;
    int lane = threadIdx.x & 63;
    int set = wid >= BB*CC; int rem = set ? wid - BB*CC : wid;
    int b = rem >> 9, i = rem & (CC-1);
    const float* A = set ? A2 : A1;
    const float* wb = w + b*CC;
    float sum = 0.f;
    for (int d = lane; d < CC; d += 64) sum += wb[d] * A[i*CC + d];
    sum = waveRedSum(sum);
    if (lane == 0) {
        float r = sum * 0.04419417382415922f + (set ? A2b : A1b)[i];
        (set ? s2 : s1)[b*CC + i] = r;
    }
}

// one wave per (set, b, o): dg = gain * rsqrt(sum_i style^2 * S2ho[o][i] + eps)
__global__ void demod_kernel(const float* __restrict__ s1, const float* __restrict__ S21,
                             const float* __restrict__ s2, const float* __restrict__ S22,
                             float* __restrict__ dg1, float* __restrict__ dg2, float gain) {
    int wid = (blockIdx.x * blockDim.x + threadIdx.x) >> 6;
    int lane = threadIdx.x & 63;
    int set = wid >= BB*CC; int rem = set ? wid - BB*CC : wid;
    int b = rem >> 9, o = rem & (CC-1);
    const float* st = (set ? s2 : s1) + b*CC;
    const float* S2 = (set ? S22 : S21) + o*CC;
    float sum = 0.f;
    for (int i = lane; i < CC; i += 64) { float sv = st[i]; sum += sv*sv*S2[i]; }
    sum = waveRedSum(sum);
    if (lane == 0) (set ? dg2 : dg1)[b*CC + o] = gain * rsqrtf(sum + 1e-8f);
}

// block = (b, p, q-group of 4), 512 threads = channels.
__global__ void upsample_mod(const float* __restrict__ x, const float* __restrict__ s1,
                             bf16* __restrict__ xs1) {
    __shared__ float usl[16][CC];
    int blk = blockIdx.x;
    int i = threadIdx.x;
    int b = blk >> 10, rem = blk & 1023, p = rem >> 4, q0 = (rem & 15) << 2;
    const float scale = 31.0f / 63.0f;
    float chf = p * scale; int h0 = (int)chf; float fh = chf - h0; int h1 = min(h0 + 1, 31);
    int wa = min(((int)(q0 * scale)) & ~3, 24);    // 4-aligned, wa+7 <= 31
    const float* xb = x + ((size_t)(b*CC + i) << 10);
    f32x4 r00 = *(const f32x4*)(xb + (h0 << 5) + wa);
    f32x4 r01 = *(const f32x4*)(xb + (h0 << 5) + wa + 4);
    f32x4 r10 = *(const f32x4*)(xb + (h1 << 5) + wa);
    f32x4 r11 = *(const f32x4*)(xb + (h1 << 5) + wa + 4);
    #pragma unroll
    for (int k = 0; k < 4; ++k) {
        usl[k][i] = r00[k]; usl[4 + k][i] = r01[k];
        usl[8 + k][i] = r10[k]; usl[12 + k][i] = r11[k];
    }
    float sv = s1[b*CC + i];
    #pragma unroll
    for (int dq = 0; dq < 4; ++dq) {
        int q = q0 + dq;
        float cwf = q * scale; int w0 = (int)cwf; float fw = cwf - w0;
        int i0 = w0 - wa, i1 = min(w0 + 1, 31) - wa;
        float v00 = usl[i0][i], v01 = usl[i1][i];
        float v10 = usl[8 + i0][i], v11 = usl[8 + i1][i];
        float va = v00*(1.f-fh) + v10*fh;
        float vb = v01*(1.f-fh) + v11*fh;
        float v  = (va*(1.f-fw) + vb*fw) * sv;
        xs1[(((b*HP) + p + 1)*HP + (q + 1))*CC + i] = (bf16)v;
    }
}

// zero only the 1-pixel halo ring of xs1/xs2 (replaces 2x 35.7MB memset).
// grid 4160 x 64 thr: one block = one halo pixel (1024 B).
__global__ void halo_zero(bf16* __restrict__ xs1, bf16* __restrict__ xs2) {
    int blk = blockIdx.x;
    bf16* dst = (blk & 1) ? xs2 : xs1;
    int idx = blk >> 1;                 // 0..2079
    int b = idx / 260, rm = idx - b*260;
    int p, q;
    if (rm < 66)       { p = 0;        q = rm; }
    else if (rm < 132) { p = 65;       q = rm - 66; }
    else if (rm < 196) { p = rm - 131; q = 0; }
    else               { p = rm - 195; q = 65; }
    f32x4* d4 = (f32x4*)(dst + ((size_t)((b*HP + p)*HP + q)) * CC);
    d4[threadIdx.x] = f32x4{0.f, 0.f, 0.f, 0.f};
}

// ---------------------------------------------------------------------------
// Implicit-GEMM 3x3 conv — r3's best-measured phase schedule, MFMA shape
// switched 16x16x32 -> 32x32x16 (2495 vs 2075 TF ceiling, half the issues).
// BM=BN=256, BK=64, 512 thr = 8 waves (2Mx4N), per-wave 128x64 as 4x2 tiles
// of 32x32 (acc = 8 x f32x16 = 128 VGPR).
// LDS identical to r3 (2 dbuf x 256x64 bf16 each for A,B; staging macros
// unchanged; row permutation LDSrow=128h+64u+q <-> m-row=128u+64h+q).
// Reads: A row (tm>>1)*128 + wm*64 + (tm&1)*32 + l31; B row tn*128 + wn*32
// + l31; slot = (2kc+(lane>>5)) ^ (lane&7) — same conflict-free XOR family.
// Phase/ledger structure verbatim from r3 (best measured: 170.6 us, 0 confl).
// C/D layout (m74/m101): col=lane&31, row=(reg&3)+8*(reg>>2)+4*(lane>>5).
// ---------------------------------------------------------------------------
#define SB  __builtin_amdgcn_sched_barrier(0)
#define BAR __builtin_amdgcn_s_barrier()
#define VMC(n)  asm volatile("s_waitcnt vmcnt(" #n ")" ::: "memory")
#define LGKM(n) asm volatile("s_waitcnt lgkmcnt(" #n ")" ::: "memory")

#define STAGE_A(d, h, U) do { \
    gload16((U) + aThr + (h)*(HP*1024),                 ldsA + (d)*32768 + (h)*16384); \
    gload16((U) + aThr + (h)*(HP*1024) + 2*(HP*1024),   ldsA + (d)*32768 + (h)*16384 + 8192); \
} while (0)

#define STAGE_B(d, h, U) do { \
    gload16((U) + bThr + (h)*32768,                     ldsB + (d)*32768 + (h)*16384); \
    gload16((U) + bThr + (h)*32768 + 131072,            ldsB + (d)*32768 + (h)*16384 + 8192); \
} while (0)

#define LOAD_A(d, fh) do { \
    _Pragma("unroll") \
    for (int tmh = 0; tmh < 2; ++tmh) { \
        _Pragma("unroll") \
        for (int kc = 0; kc < 4; ++kc) \
            afr[tmh][kc] = *(const bf16x8*)(aRd + (d)*32768 + (fh)*16384 + tmh*4096 + swz[kc]); \
    } } while (0)

#define LOAD_B(d, tn) do { \
    _Pragma("unroll") \
    for (int kc = 0; kc < 4; ++kc) \
        bfr[tn][kc] = *(const bf16x8*)(bRd + (d)*32768 + (tn)*16384 + swz[kc]); \
    } while (0)

#define QUAD(fh, tn) do { \
    __builtin_amdgcn_s_setprio(1); \
    _Pragma("unroll") \
    for (int kc = 0; kc < 4; ++kc) \
    { _Pragma("unroll") \
      for (int tmh = 0; tmh < 2; ++tmh) \
        acc[(fh)*2+tmh][tn] = __builtin_amdgcn_mfma_f32_32x32x16_bf16( \
            afr[tmh][kc], bfr[tn][kc], acc[(fh)*2+tmh][tn], 0, 0, 0); } \
    __builtin_amdgcn_s_setprio(0); } while (0)

// one K-step = 4 phases. cur/nxt are dbuf indices (compile-time).
// aN1/bN1: staging bases for step s+1; aN2: for step s+2 (into dbuf cur).
#define PHSTEP(cur, nxt, aN1, bN1, aN2, g1, g3) do { \
    /* phase 0: Q(0,0) */ \
    LOAD_A(cur, 0); \
    LOAD_B(cur, 0); \
    if (g1) STAGE_B(nxt, 0, bN1); \
    LGKM(8); SB; BAR; LGKM(0); SB; \
    QUAD(0, 0); \
    VMC(4); SB; BAR; SB; \
    /* phase 1: Q(0,1) */ \
    LOAD_B(cur, 1); \
    if (g1) STAGE_B(nxt, 1, bN1); \
    SB; BAR; LGKM(0); SB; \
    QUAD(0, 1); \
    SB; BAR; SB; \
    /* phase 2: Q(1,1) */ \
    LOAD_A(cur, 1); \
    if (g1) STAGE_A(nxt, 1, aN1); \
    SB; BAR; LGKM(0); SB; \
    QUAD(1, 1); \
    SB; BAR; SB; \
    /* phase 3: Q(1,0) */ \
    if (g3) STAGE_A(cur, 0, aN2); \
    SB; BAR; SB; \
    QUAD(1, 0); \
    if (g3) { VMC(6); } else { VMC(0); } \
    SB; BAR; SB; \
} while (0)

template<int PHASE>
__global__ __launch_bounds__(512, 1) void conv_gemm(
    const bf16* __restrict__ xs, const bf16* __restrict__ keffT,
    const float* __restrict__ dg, const float* __restrict__ noise,
    const float* __restrict__ nsw, const float* __restrict__ nsb,
    const float* __restrict__ nbw, const float* __restrict__ nbb,
    const float* __restrict__ biasv, const float* __restrict__ stnext,
    bf16* __restrict__ outb, float* __restrict__ outf) {
    __shared__ __attribute__((aligned(16))) bf16 As[32768];   // 64 KB: 2 dbuf x 256x64
    __shared__ __attribute__((aligned(16))) bf16 Bs[32768];   // 64 KB
    const int tid = threadIdx.x;
    const int wave = tid >> 6, lane = tid & 63;
    // XCD swizzle: 256 wgs, %8==0 -> bijective.
    const int tileId = ((blockIdx.x & 7) << 5) + (blockIdx.x >> 3);
    const int mtile = tileId >> 1, ntile = tileId & 1;
    const int m0 = mtile << 8, n0 = ntile << 8;
    const int b  = m0 >> 12;
    const int p0 = (m0 & 4095) >> 6;
    const int wm = wave >> 2, wn = wave & 3;
    const int l31 = lane & 31;

    // staging thread constants (source pre-XOR-swizzled, dest linear) — as r3
    const int srcSwz = (((tid & 7) ^ ((tid >> 3) & 7)) << 4);
    const int aThr = ((tid >> 3) << 10) + srcSwz;
    const int bThr = (((tid >> 8) & 1) << 16) + (((tid >> 3) & 31) << 10) + srcSwz;
    char* const ldsA = (char*)As + tid*16;
    char* const ldsB = (char*)Bs + tid*16;

    // fragment read bases (32x32 tiles)
    const char* const aRd = (const char*)As + (wm << 13) + (l31 << 7);
    const char* const bRd = (const char*)Bs + (((wn << 5) + l31) << 7);
    int swz[4];
    #pragma unroll
    for (int kc = 0; kc < 4; ++kc)
        swz[kc] = ((((kc << 1) | (lane >> 5)) ^ (lane & 7)) << 4);

    f32x16 acc[4][2];
    #pragma unroll
    for (int i_ = 0; i_ < 4; ++i_)
        #pragma unroll
        for (int j_ = 0; j_ < 2; ++j_)
            #pragma unroll
            for (int e_ = 0; e_ < 16; ++e_) acc[i_][j_][e_] = 0.f;
    bf16x8 afr[2][4], bfr[2][4];

    // staging bases per K-step st (0..71): tap t=st>>3, k0=(st&7)*64
    auto abase = [&](int st) -> const char* {
        int t = st >> 3; int dh = (t*11) >> 5; int dw = t - dh*3;
        return (const char*)xs + ((size_t)((b*HP + p0 + dh)*HP + dw) << 10) + ((st & 7) << 7);
    };
    auto bbase = [&](int st) -> const char* {
        int t = st >> 3;
        return (const char*)keffT + ((size_t)(t*CC + n0) << 10) + ((st & 7) << 7);
    };

    // prologue: stage units 0..4 in read order, leave units 2..4 in flight
    {
        const char* a0 = abase(0); const char* b0 = bbase(0); const char* a1 = abase(1);
        STAGE_A(0, 0, a0);
        STAGE_B(0, 0, b0);
        STAGE_B(0, 1, b0);
        STAGE_A(0, 1, a0);
        STAGE_A(1, 0, a1);
        VMC(6); SB; BAR; SB;
    }

    #pragma unroll 1
    for (int it = 0; it < 36; ++it) {
        const bool more = (it < 35);
        const char* aE = abase(2*it + 1); const char* bE = bbase(2*it + 1);
        const char* aO = abase(2*it + 2); const char* bO = bbase(2*it + 2);
        const char* aO2 = abase(2*it + 3);
        PHSTEP(0, 1, aE, bE, aO,  true, more);   // compute K-step 2it   (dbuf0)
        PHSTEP(1, 0, aO, bO, aO2, more, more);   // compute K-step 2it+1 (dbuf1)
    }

    // epilogue: v*dg -> noise modulation -> +bias -> lrelu -> route
    // 32x32 C/D: col = lane&31, row = (reg&3) + 8*(reg>>2) + 4*(lane>>5)
    const float* dgb = dg + b*CC;
    int nIdx[2]; float pdg[2], pnsw[2], pnsb[2], pnbw[2], pnbb[2], pbias[2], pst[2];
    #pragma unroll
    for (int tn = 0; tn < 2; ++tn) {
        int n = n0 + (wn << 6) + (tn << 5) + l31;
        nIdx[tn] = n;
        pdg[tn] = dgb[n]; pnsw[tn] = nsw[n]; pnsb[tn] = nsb[n];
        pnbw[tn] = nbw[n]; pnbb[tn] = nbb[n]; pbias[tn] = biasv[n];
        if (PHASE == 1) pst[tn] = stnext[b*CC + n]; else pst[tn] = 0.f;
    }
    #pragma unroll
    for (int tm = 0; tm < 4; ++tm) {
        #pragma unroll
        for (int rq = 0; rq < 4; ++rq) {
            int mbase = m0 + (wm << 7) + (tm << 5) + (rq << 3) + ((lane >> 5) << 2);
            #pragma unroll
            for (int rr = 0; rr < 4; ++rr) {
                int mloc = mbase + rr;
                float ns = noise[mloc];
                int prow = (mloc & 4095) >> 6, qcol = mloc & 63;
                #pragma unroll
                for (int tn = 0; tn < 2; ++tn) {
                    float v = acc[tm][tn][rq*4 + rr] * pdg[tn];
                    v = v * (ns*pnsw[tn] + pnsb[tn]) + (ns*pnbw[tn] + pnbb[tn]) + pbias[tn];
                    v = fmaxf(v, 0.2f*v);   // leaky relu 0.2
                    if (PHASE == 1) {
                        outb[(((b*HP) + prow + 1)*HP + (qcol + 1))*CC + nIdx[tn]] =
                            (bf16)(v * pst[tn]);
                    } else {
                        outf[((b*CC + nIdx[tn]) << 12) + (mloc & 4095)] = v;
                    }
                }
            }
        }
    }
}

// block = 64 consecutive pixels, 4 waves split the o-range (128 each).
__global__ void rgb_kernel(const float* __restrict__ xf, const float* __restrict__ rgbw,
                           const float* __restrict__ rgbb, float* __restrict__ out) {
    __shared__ float red[3][4][64];
    int tid = threadIdx.x;
    int wv = tid >> 6, ln = tid & 63;
    int pix = blockIdx.x * 64 + ln;
    int b = pix >> 12, rem = pix & 4095;
    const float* xb = xf + (((size_t)b*CC) << 12) + rem;
    float a0 = 0.f, a1 = 0.f, a2 = 0.f;
    int o0 = wv << 7;
    #pragma unroll 8
    for (int o = o0; o < o0 + 128; ++o) {
        float xv = xb[(size_t)o << 12];
        a0 += xv * rgbw[o]; a1 += xv * rgbw[CC+o]; a2 += xv * rgbw[2*CC+o];
    }
    red[0][wv][ln] = a0; red[1][wv][ln] = a1; red[2][wv][ln] = a2;
    __syncthreads();
    if (wv == 0) {
        const float he = 0.03f * 0.04419417382415922f;
        #pragma unroll
        for (int c = 0; c < 3; ++c) {
            float s = red[c][0][ln] + red[c][1][ln] + red[c][2][ln] + red[c][3][ln];
            out[(b*3+c)*4096 + rem] = s*he + rgbb[c];
        }
    }
}

extern "C" void kernel_launch(void* const* d_in, const int* in_sizes, int n_in,
                              void* d_out, int out_size, void* d_ws, size_t ws_size,
                              hipStream_t stream) {
    const float* x      = (const float*)d_in[0];
    const float* w      = (const float*)d_in[1];
    const float* noise1 = (const float*)d_in[2];
    const float* noise2 = (const float*)d_in[3];
    const float* conv1w = (const float*)d_in[4];
    const float* bias1  = (const float*)d_in[5];
    const float* conv2w = (const float*)d_in[6];
    const float* bias2  = (const float*)d_in[7];
    const float* A1w = (const float*)d_in[8];
    const float* A1b = (const float*)d_in[9];
    const float* A2w = (const float*)d_in[10];
    const float* A2b = (const float*)d_in[11];
    const float* B1sw = (const float*)d_in[12];
    const float* B1sb = (const float*)d_in[13];
    const float* B1bw = (const float*)d_in[14];
    const float* B1bb = (const float*)d_in[15];
    const float* B2sw = (const float*)d_in[16];
    const float* B2sb = (const float*)d_in[17];
    const float* B2bw = (const float*)d_in[18];
    const float* B2bb = (const float*)d_in[19];
    const float* rgbw = (const float*)d_in[20];
    const float* rgbb = (const float*)d_in[21];

    char* ws = (char*)d_ws;
    size_t off = 0;
    auto alloc = [&](size_t bytes) { char* p = ws + off; off += (bytes + 255) & ~(size_t)255; return p; };
    const size_t xsBytes = (size_t)BB*HP*HP*CC*2;
    bf16* xs1 = (bf16*)alloc(xsBytes);
    bf16* xs2 = (bf16*)alloc(xsBytes);
    bf16* kT1 = (bf16*)alloc((size_t)9*CC*CC*2);
    bf16* kT2 = (bf16*)alloc((size_t)9*CC*CC*2);
    float* S21 = (float*)alloc((size_t)CC*CC*4);
    float* S22 = (float*)alloc((size_t)CC*CC*4);
    float* s1  = (float*)alloc(BB*CC*4);
    float* s2  = (float*)alloc(BB*CC*4);
    float* dg1 = (float*)alloc(BB*CC*4);
    float* dg2 = (float*)alloc(BB*CC*4);

    float* outx   = (float*)d_out;
    float* outrgb = outx + (size_t)BB*CC*HO*HO;

    const float gain = 1.41421356237309515f;
    const float he = gain / sqrtf(512.f * 9.f);
    halo_zero<<<4160, 64, 0, stream>>>(xs1, xs2);
    prep_weights<<<CC*CC/256, 256, 0, stream>>>(conv1w, S21, kT1, he);
    prep_weights<<<CC*CC/256, 256, 0, stream>>>(conv2w, S22, kT2, he);
    style_kernel<<<2*BB*CC/4, 256, 0, stream>>>(w, A1w, A1b, A2w, A2b, s1, s2);
    demod_kernel<<<2*BB*CC/4, 256, 0, stream>>>(s1, S21, s2, S22, dg1, dg2, gain);
    upsample_mod<<<BB*HO*16, CC, 0, stream>>>(x, s1, xs1);
    conv_gemm<1><<<(NPIX/256)*(CC/256), 512, 0, stream>>>(
        xs1, kT1, dg1, noise1, B1sw, B1sb, B1bw, B1bb, bias1, s2, xs2, nullptr);
    conv_gemm<2><<<(NPIX/256)*(CC/256), 512, 0, stream>>>(
        xs2, kT2, dg2, noise2, B2sw, B2sb, B2bw, B2bb, bias2, nullptr, nullptr, outx);
    rgb_kernel<<<NPIX/64, 256, 0, stream>>>(outx, rgbw, rgbb, outrgb);
}

// Round 7
// 356.431 us; speedup vs baseline: 1.1801x; 1.1801x over previous
//
#include <hip/hip_runtime.h>
#include <hip/hip_bf16.h>

#define BB 8
#define CC 512
#define HO 64
#define HP 66
#define NPIX (BB*HO*HO)   // 32768

typedef float f32x4 __attribute__((ext_vector_type(4)));
typedef __bf16 bf16x8 __attribute__((ext_vector_type(8)));
using bf16 = __hip_bfloat16;

__device__ __forceinline__ void gload16(const void* g, void* l) {
    __builtin_amdgcn_global_load_lds((const __attribute__((address_space(1))) void*)g,
                                     (__attribute__((address_space(3))) void*)l, 16, 0, 0);
}

__device__ __forceinline__ float waveRedSum(float v) {
    #pragma unroll
    for (int off = 32; off; off >>= 1) v += __shfl_down(v, off);
    return v;
}

// thread t -> (i = t&511, o = t>>9). Reads W[i][o][0..8] (contiguous 36B),
// writes S2ho[o][i] = he^2 * sum W^2, and keffT[tap][o][i] = he*W[i][o][8-tap].
__global__ void prep_weights(const float* __restrict__ Wsrc, float* __restrict__ S2ho,
                             bf16* __restrict__ keffT, float he) {
    int t = blockIdx.x * blockDim.x + threadIdx.x;
    int i = t & (CC-1), o = t >> 9;
    const float* wp = Wsrc + (i*CC + o)*9;
    float v[9]; float s2 = 0.f;
    #pragma unroll
    for (int k = 0; k < 9; ++k) { v[k] = wp[k] * he; s2 += v[k]*v[k]; }
    S2ho[o*CC + i] = s2;
    #pragma unroll
    for (int tp = 0; tp < 9; ++tp) keffT[(tp*CC + o)*CC + i] = (bf16)v[8 - tp];
}

// one wave per (set, b, i): style[b,i] = sum_d w[b,d]*A[i,d]/sqrt(512) + Ab[i]
__global__ void style_kernel(const float* __restrict__ w,
                             const float* __restrict__ A1, const float* __restrict__ A1b,
                             const float* __restrict__ A2, const float* __restrict__ A2b,
                             float* __restrict__ s1, float* __restrict__ s2) {
    int wid = (blockIdx.x * blockDim.x + threadIdx.x) >> 6;
    int lane = threadIdx.x & 63;
    int set = wid >= BB*CC; int rem = set ? wid - BB*CC : wid;
    int b = rem >> 9, i = rem & (CC-1);
    const float* A = set ? A2 : A1;
    const float* wb = w + b*CC;
    float sum = 0.f;
    for (int d = lane; d < CC; d += 64) sum += wb[d] * A[i*CC + d];
    sum = waveRedSum(sum);
    if (lane == 0) {
        float r = sum * 0.04419417382415922f + (set ? A2b : A1b)[i];
        (set ? s2 : s1)[b*CC + i] = r;
    }
}

// one wave per (set, b, o): dg = gain * rsqrt(sum_i style^2 * S2ho[o][i] + eps)
__global__ void demod_kernel(const float* __restrict__ s1, const float* __restrict__ S21,
                             const float* __restrict__ s2, const float* __restrict__ S22,
                             float* __restrict__ dg1, float* __restrict__ dg2, float gain) {
    int wid = (blockIdx.x * blockDim.x + threadIdx.x) >> 6;
    int lane = threadIdx.x & 63;
    int set = wid >= BB*CC; int rem = set ? wid - BB*CC : wid;
    int b = rem >> 9, o = rem & (CC-1);
    const float* st = (set ? s2 : s1) + b*CC;
    const float* S2 = (set ? S22 : S21) + o*CC;
    float sum = 0.f;
    for (int i = lane; i < CC; i += 64) { float sv = st[i]; sum += sv*sv*S2[i]; }
    sum = waveRedSum(sum);
    if (lane == 0) (set ? dg2 : dg1)[b*CC + o] = gain * rsqrtf(sum + 1e-8f);
}

// block = (b, p, q-group of 4), 512 threads = channels.
__global__ void upsample_mod(const float* __restrict__ x, const float* __restrict__ s1,
                             bf16* __restrict__ xs1) {
    __shared__ float usl[16][CC];
    int blk = blockIdx.x;
    int i = threadIdx.x;
    int b = blk >> 10, rem = blk & 1023, p = rem >> 4, q0 = (rem & 15) << 2;
    const float scale = 31.0f / 63.0f;
    float chf = p * scale; int h0 = (int)chf; float fh = chf - h0; int h1 = min(h0 + 1, 31);
    int wa = min(((int)(q0 * scale)) & ~3, 24);    // 4-aligned, wa+7 <= 31
    const float* xb = x + ((size_t)(b*CC + i) << 10);
    f32x4 r00 = *(const f32x4*)(xb + (h0 << 5) + wa);
    f32x4 r01 = *(const f32x4*)(xb + (h0 << 5) + wa + 4);
    f32x4 r10 = *(const f32x4*)(xb + (h1 << 5) + wa);
    f32x4 r11 = *(const f32x4*)(xb + (h1 << 5) + wa + 4);
    #pragma unroll
    for (int k = 0; k < 4; ++k) {
        usl[k][i] = r00[k]; usl[4 + k][i] = r01[k];
        usl[8 + k][i] = r10[k]; usl[12 + k][i] = r11[k];
    }
    float sv = s1[b*CC + i];
    #pragma unroll
    for (int dq = 0; dq < 4; ++dq) {
        int q = q0 + dq;
        float cwf = q * scale; int w0 = (int)cwf; float fw = cwf - w0;
        int i0 = w0 - wa, i1 = min(w0 + 1, 31) - wa;
        float v00 = usl[i0][i], v01 = usl[i1][i];
        float v10 = usl[8 + i0][i], v11 = usl[8 + i1][i];
        float va = v00*(1.f-fh) + v10*fh;
        float vb = v01*(1.f-fh) + v11*fh;
        float v  = (va*(1.f-fw) + vb*fw) * sv;
        xs1[(((b*HP) + p + 1)*HP + (q + 1))*CC + i] = (bf16)v;
    }
}

// zero only the 1-pixel halo ring of xs1/xs2 (replaces 2x 35.7MB memset).
// grid 4160 x 64 thr: one block = one halo pixel (1024 B).
__global__ void halo_zero(bf16* __restrict__ xs1, bf16* __restrict__ xs2) {
    int blk = blockIdx.x;
    bf16* dst = (blk & 1) ? xs2 : xs1;
    int idx = blk >> 1;                 // 0..2079
    int b = idx / 260, rm = idx - b*260;
    int p, q;
    if (rm < 66)       { p = 0;        q = rm; }
    else if (rm < 132) { p = 65;       q = rm - 66; }
    else if (rm < 196) { p = rm - 131; q = 0; }
    else               { p = rm - 195; q = 65; }
    f32x4* d4 = (f32x4*)(dst + ((size_t)((b*HP + p)*HP + q)) * CC);
    d4[threadIdx.x] = f32x4{0.f, 0.f, 0.f, 0.f};
}

// ---------------------------------------------------------------------------
// Implicit-GEMM 3x3 conv, m201-faithful 8-phase schedule (T2+T3+T4+T5).
// BM=BN=256, BK=64, 512 thr = 8 waves (2Mx4N), per-wave 128x64.
// [r3 verbatim — best measured: 170.6 us, MfmaUtil 38%, 0 bank conflicts.
//  r6's 32x32-MFMA variant regressed (intrinsic 4-way LDS conflict at 128B
//  rows: 32 rows/instr share slot groups keyed on row&7). 16x16 is correct.]
// Per phase: {ds_read subtile || stage 1 half-tile} -> s_barrier -> lgkmcnt(0)
// -> 16 MFMA (setprio 1) -> [counted vmcnt] -> s_barrier.
// Staging stream depth 5 phases; vmcnt(4) at ph0 end, vmcnt(6) at ph3 end;
// tail drains vmcnt(0). Slot-XOR swizzle (slot ^ row&7) both sides.
// ---------------------------------------------------------------------------
#define SB  __builtin_amdgcn_sched_barrier(0)
#define BAR __builtin_amdgcn_s_barrier()
#define VMC(n)  asm volatile("s_waitcnt vmcnt(" #n ")" ::: "memory")
#define LGKM(n) asm volatile("s_waitcnt lgkmcnt(" #n ")" ::: "memory")

#define STAGE_A(d, h, U) do { \
    gload16((U) + aThr + (h)*(HP*1024),                 ldsA + (d)*32768 + (h)*16384); \
    gload16((U) + aThr + (h)*(HP*1024) + 2*(HP*1024),   ldsA + (d)*32768 + (h)*16384 + 8192); \
} while (0)

#define STAGE_B(d, h, U) do { \
    gload16((U) + bThr + (h)*32768,                     ldsB + (d)*32768 + (h)*16384); \
    gload16((U) + bThr + (h)*32768 + 131072,            ldsB + (d)*32768 + (h)*16384 + 8192); \
} while (0)

#define LOAD_A(d, fh) do { \
    _Pragma("unroll") \
    for (int fmq = 0; fmq < 4; ++fmq) { \
        afr[fmq][0] = *(const bf16x8*)(aRd + (d)*32768 + (fh)*16384 + fmq*2048 + swz0); \
        afr[fmq][1] = *(const bf16x8*)(aRd + (d)*32768 + (fh)*16384 + fmq*2048 + swz1); \
    } } while (0)

#define LOAD_B(d, nh) do { \
    _Pragma("unroll") \
    for (int fnq = 0; fnq < 2; ++fnq) { \
        bfr[nh][fnq][0] = *(const bf16x8*)(bRd + (d)*32768 + (nh)*16384 + fnq*2048 + swz0); \
        bfr[nh][fnq][1] = *(const bf16x8*)(bRd + (d)*32768 + (nh)*16384 + fnq*2048 + swz1); \
    } } while (0)

#define QUAD(fh, nh) do { \
    __builtin_amdgcn_s_setprio(1); \
    _Pragma("unroll") \
    for (int kc = 0; kc < 2; ++kc) \
    { _Pragma("unroll") \
      for (int fmq = 0; fmq < 4; ++fmq) \
      { _Pragma("unroll") \
        for (int fnq = 0; fnq < 2; ++fnq) \
            acc[(fh)*4+fmq][(nh)*2+fnq] = __builtin_amdgcn_mfma_f32_16x16x32_bf16( \
                afr[fmq][kc], bfr[nh][fnq][kc], acc[(fh)*4+fmq][(nh)*2+fnq], 0, 0, 0); } } \
    __builtin_amdgcn_s_setprio(0); } while (0)

// one K-step = 4 phases. cur/nxt are dbuf indices (compile-time).
// aN1/bN1: staging bases for step s+1; aN2: for step s+2 (into dbuf cur).
#define PHSTEP(cur, nxt, aN1, bN1, aN2, g1, g3) do { \
    /* phase 0: Q(0,0) */ \
    LOAD_A(cur, 0); \
    LOAD_B(cur, 0); \
    if (g1) STAGE_B(nxt, 0, bN1); \
    LGKM(8); SB; BAR; LGKM(0); SB; \
    QUAD(0, 0); \
    VMC(4); SB; BAR; SB; \
    /* phase 1: Q(0,1) */ \
    LOAD_B(cur, 1); \
    if (g1) STAGE_B(nxt, 1, bN1); \
    SB; BAR; LGKM(0); SB; \
    QUAD(0, 1); \
    SB; BAR; SB; \
    /* phase 2: Q(1,1) */ \
    LOAD_A(cur, 1); \
    if (g1) STAGE_A(nxt, 1, aN1); \
    SB; BAR; LGKM(0); SB; \
    QUAD(1, 1); \
    SB; BAR; SB; \
    /* phase 3: Q(1,0) */ \
    if (g3) STAGE_A(cur, 0, aN2); \
    SB; BAR; SB; \
    QUAD(1, 0); \
    if (g3) { VMC(6); } else { VMC(0); } \
    SB; BAR; SB; \
} while (0)

template<int PHASE>
__global__ __launch_bounds__(512, 2) void conv_gemm(
    const bf16* __restrict__ xs, const bf16* __restrict__ keffT,
    const float* __restrict__ dg, const float* __restrict__ noise,
    const float* __restrict__ nsw, const float* __restrict__ nsb,
    const float* __restrict__ nbw, const float* __restrict__ nbb,
    const float* __restrict__ biasv, const float* __restrict__ stnext,
    bf16* __restrict__ outb, float* __restrict__ outf) {
    __shared__ __attribute__((aligned(16))) bf16 As[32768];   // 64 KB: 2 dbuf x 256x64
    __shared__ __attribute__((aligned(16))) bf16 Bs[32768];   // 64 KB
    const int tid = threadIdx.x;
    const int wave = tid >> 6, lane = tid & 63;
    // XCD swizzle: 256 wgs, %8==0 -> bijective.
    const int tileId = ((blockIdx.x & 7) << 5) + (blockIdx.x >> 3);
    const int mtile = tileId >> 1, ntile = tileId & 1;
    const int m0 = mtile << 8, n0 = ntile << 8;
    const int b  = m0 >> 12;
    const int p0 = (m0 & 4095) >> 6;
    const int wm = wave >> 2, wn = wave & 3;
    const int l15 = lane & 15;

    // staging thread constants (source pre-XOR-swizzled, dest linear)
    const int srcSwz = (((tid & 7) ^ ((tid >> 3) & 7)) << 4);
    const int aThr = ((tid >> 3) << 10) + srcSwz;
    const int bThr = (((tid >> 8) & 1) << 16) + (((tid >> 3) & 31) << 10) + srcSwz;
    char* const ldsA = (char*)As + tid*16;
    char* const ldsB = (char*)Bs + tid*16;

    // fragment read bases (row*128 + (slot ^ row&7)*16)
    const char* const aRd = (const char*)As + (((wm << 6) + l15) << 7);
    const char* const bRd = (const char*)Bs + (((wn << 5) + l15) << 7);
    const int swz0 = (((lane >> 4)    ) ^ (lane & 7)) << 4;
    const int swz1 = (((lane >> 4) | 4) ^ (lane & 7)) << 4;

    f32x4 acc[8][4];
    #pragma unroll
    for (int i_ = 0; i_ < 8; ++i_)
        #pragma unroll
        for (int j_ = 0; j_ < 4; ++j_) acc[i_][j_] = f32x4{0.f, 0.f, 0.f, 0.f};
    bf16x8 afr[4][2], bfr[2][2][2];

    // uniform staging bases per K-step st (0..71): tap t=st>>3, k0=(st&7)*64
    auto abase = [&](int st) -> const char* {
        int t = st >> 3; int dh = (t*11) >> 5; int dw = t - dh*3;
        return (const char*)xs + ((size_t)((b*HP + p0 + dh)*HP + dw) << 10) + ((st & 7) << 7);
    };
    auto bbase = [&](int st) -> const char* {
        int t = st >> 3;
        return (const char*)keffT + ((size_t)(t*CC + n0) << 10) + ((st & 7) << 7);
    };

    // prologue: stage units 0..4 in read order, leave units 2..4 in flight
    {
        const char* a0 = abase(0); const char* b0 = bbase(0); const char* a1 = abase(1);
        STAGE_A(0, 0, a0);
        STAGE_B(0, 0, b0);
        STAGE_B(0, 1, b0);
        STAGE_A(0, 1, a0);
        STAGE_A(1, 0, a1);
        VMC(6); SB; BAR; SB;
    }

    #pragma unroll 1
    for (int it = 0; it < 36; ++it) {
        const bool more = (it < 35);
        const char* aE = abase(2*it + 1); const char* bE = bbase(2*it + 1);
        const char* aO = abase(2*it + 2); const char* bO = bbase(2*it + 2);
        const char* aO2 = abase(2*it + 3);
        PHSTEP(0, 1, aE, bE, aO,  true, more);   // compute K-step 2it   (dbuf0)
        PHSTEP(1, 0, aO, bO, aO2, more, more);   // compute K-step 2it+1 (dbuf1)
    }

    // epilogue: v*dg -> noise modulation -> +bias -> lrelu -> route
    const float* dgb = dg + b*CC;
    int nIdx[4]; float pdg[4], pnsw[4], pnsb[4], pnbw[4], pnbb[4], pbias[4], pst[4];
    #pragma unroll
    for (int fn = 0; fn < 4; ++fn) {
        int n = n0 + (wn << 6) + (fn << 4) + l15;
        nIdx[fn] = n;
        pdg[fn] = dgb[n]; pnsw[fn] = nsw[n]; pnsb[fn] = nsb[n];
        pnbw[fn] = nbw[n]; pnbb[fn] = nbb[n]; pbias[fn] = biasv[n];
        if (PHASE == 1) pst[fn] = stnext[b*CC + n]; else pst[fn] = 0.f;
    }
    #pragma unroll
    for (int fm = 0; fm < 8; ++fm) {
        const int mbase = m0 + (wm << 7) + (fm << 4) + ((lane >> 4) << 2);
        const f32x4 nsv = *(const f32x4*)(noise + mbase);   // 4 consecutive pixels
        if (PHASE == 2) {
            #pragma unroll
            for (int fn = 0; fn < 4; ++fn) {
                f32x4 vv;
                #pragma unroll
                for (int r = 0; r < 4; ++r) {
                    float ns = nsv[r];
                    float v = acc[fm][fn][r] * pdg[fn];
                    v = v * (ns*pnsw[fn] + pnsb[fn]) + (ns*pnbw[fn] + pnbb[fn]) + pbias[fn];
                    vv[r] = fmaxf(v, 0.2f*v);
                }
                *(f32x4*)(outf + ((size_t)(b*CC + nIdx[fn]) << 12) + (mbase & 4095)) = vv;
            }
        } else {
            #pragma unroll
            for (int r = 0; r < 4; ++r) {
                int mloc = mbase + r;
                float ns = nsv[r];
                int prow = (mloc & 4095) >> 6, qcol = mloc & 63;
                #pragma unroll
                for (int fn = 0; fn < 4; ++fn) {
                    float v = acc[fm][fn][r] * pdg[fn];
                    v = v * (ns*pnsw[fn] + pnsb[fn]) + (ns*pnbw[fn] + pnbb[fn]) + pbias[fn];
                    v = fmaxf(v, 0.2f*v);   // leaky relu 0.2
                    outb[(((b*HP) + prow + 1)*HP + (qcol + 1))*CC + nIdx[fn]] =
                        (bf16)(v * pst[fn]);
                }
            }
        }
    }
}

// block = 64 consecutive pixels, 4 waves split the o-range (128 each).
__global__ void rgb_kernel(const float* __restrict__ xf, const float* __restrict__ rgbw,
                           const float* __restrict__ rgbb, float* __restrict__ out) {
    __shared__ float red[3][4][64];
    int tid = threadIdx.x;
    int wv = tid >> 6, ln = tid & 63;
    int pix = blockIdx.x * 64 + ln;
    int b = pix >> 12, rem = pix & 4095;
    const float* xb = xf + (((size_t)b*CC) << 12) + rem;
    float a0 = 0.f, a1 = 0.f, a2 = 0.f;
    int o0 = wv << 7;
    #pragma unroll 8
    for (int o = o0; o < o0 + 128; ++o) {
        float xv = xb[(size_t)o << 12];
        a0 += xv * rgbw[o]; a1 += xv * rgbw[CC+o]; a2 += xv * rgbw[2*CC+o];
    }
    red[0][wv][ln] = a0; red[1][wv][ln] = a1; red[2][wv][ln] = a2;
    __syncthreads();
    if (wv == 0) {
        const float he = 0.03f * 0.04419417382415922f;
        #pragma unroll
        for (int c = 0; c < 3; ++c) {
            float s = red[c][0][ln] + red[c][1][ln] + red[c][2][ln] + red[c][3][ln];
            out[(b*3+c)*4096 + rem] = s*he + rgbb[c];
        }
    }
}

extern "C" void kernel_launch(void* const* d_in, const int* in_sizes, int n_in,
                              void* d_out, int out_size, void* d_ws, size_t ws_size,
                              hipStream_t stream) {
    const float* x      = (const float*)d_in[0];
    const float* w      = (const float*)d_in[1];
    const float* noise1 = (const float*)d_in[2];
    const float* noise2 = (const float*)d_in[3];
    const float* conv1w = (const float*)d_in[4];
    const float* bias1  = (const float*)d_in[5];
    const float* conv2w = (const float*)d_in[6];
    const float* bias2  = (const float*)d_in[7];
    const float* A1w = (const float*)d_in[8];
    const float* A1b = (const float*)d_in[9];
    const float* A2w = (const float*)d_in[10];
    const float* A2b = (const float*)d_in[11];
    const float* B1sw = (const float*)d_in[12];
    const float* B1sb = (const float*)d_in[13];
    const float* B1bw = (const float*)d_in[14];
    const float* B1bb = (const float*)d_in[15];
    const float* B2sw = (const float*)d_in[16];
    const float* B2sb = (const float*)d_in[17];
    const float* B2bw = (const float*)d_in[18];
    const float* B2bb = (const float*)d_in[19];
    const float* rgbw = (const float*)d_in[20];
    const float* rgbb = (const float*)d_in[21];

    char* ws = (char*)d_ws;
    size_t off = 0;
    auto alloc = [&](size_t bytes) { char* p = ws + off; off += (bytes + 255) & ~(size_t)255; return p; };
    const size_t xsBytes = (size_t)BB*HP*HP*CC*2;
    bf16* xs1 = (bf16*)alloc(xsBytes);
    bf16* xs2 = (bf16*)alloc(xsBytes);
    bf16* kT1 = (bf16*)alloc((size_t)9*CC*CC*2);
    bf16* kT2 = (bf16*)alloc((size_t)9*CC*CC*2);
    float* S21 = (float*)alloc((size_t)CC*CC*4);
    float* S22 = (float*)alloc((size_t)CC*CC*4);
    float* s1  = (float*)alloc(BB*CC*4);
    float* s2  = (float*)alloc(BB*CC*4);
    float* dg1 = (float*)alloc(BB*CC*4);
    float* dg2 = (float*)alloc(BB*CC*4);

    float* outx   = (float*)d_out;
    float* outrgb = outx + (size_t)BB*CC*HO*HO;

    const float gain = 1.41421356237309515f;
    const float he = gain / sqrtf(512.f * 9.f);
    halo_zero<<<4160, 64, 0, stream>>>(xs1, xs2);
    prep_weights<<<CC*CC/256, 256, 0, stream>>>(conv1w, S21, kT1, he);
    prep_weights<<<CC*CC/256, 256, 0, stream>>>(conv2w, S22, kT2, he);
    style_kernel<<<2*BB*CC/4, 256, 0, stream>>>(w, A1w, A1b, A2w, A2b, s1, s2);
    demod_kernel<<<2*BB*CC/4, 256, 0, stream>>>(s1, S21, s2, S22, dg1, dg2, gain);
    upsample_mod<<<BB*HO*16, CC, 0, stream>>>(x, s1, xs1);
    conv_gemm<1><<<(NPIX/256)*(CC/256), 512, 0, stream>>>(
        xs1, kT1, dg1, noise1, B1sw, B1sb, B1bw, B1bb, bias1, s2, xs2, nullptr);
    conv_gemm<2><<<(NPIX/256)*(CC/256), 512, 0, stream>>>(
        xs2, kT2, dg2, noise2, B2sw, B2sb, B2bw, B2bb, bias2, nullptr, nullptr, outx);
    rgb_kernel<<<NPIX/64, 256, 0, stream>>>(outx, rgbw, rgbb, outrgb);
}